// Round 16
// baseline (284.508 us; speedup 1.0000x reference)
//
#include <hip/hip_runtime.h>
#include <hip/hip_fp16.h>

// Problem constants (fixed by the reference file)
#define NN 50000     // nodes
#define NE 800000    // edges
#define HD 64        // feature dim (in and hidden)
#define NG 512       // graphs
#define NBK 196      // buckets: col >> 8, max 49999>>8 = 195
#define NBL 196      // edge blocks of 4096: ceil(NE/4096)
#define M_CNT (NBK * NBL)       // 38416 counts
#define NBS 151                 // scan blocks: ceil(M_CNT/256)
#define GEMM_BLOCKS 3125        // NN/16

// Math: with h' = dinv*h stored as fp8 E5M2 (= fp16 top byte; encode RN via
// (bits+0x80)>>8, decode exact via <<8):
//   out[c] = dinv[c] * (sum_src h'[src] + h'[c]) + b.
// Why fp8: the gathered array drops to 3.2 MB (fits EVERY per-XCD 4 MiB L2,
// killing the ~34% HBM-miss latency) and rows are 64 B (halving cache-line
// requests). R11..R15 showed the gather is memory-queue-bound (~46-54 µs
// regardless of instruction mix); this attacks the queue directly.
// Gather keeps R15's proven shape: node-per-wave, scalar esrc stream, ONE
// masked 16-edge tail batch (clamped srcs, zero-multiplied), no shuffles in
// loops (R8/R10 bug class), no LDS atomics (R14).

__device__ __forceinline__ unsigned char cv8(float f) {
    return (unsigned char)((__half_as_ushort(__float2half(f)) + 0x80) >> 8);
}

__device__ __forceinline__ float4 exp8(unsigned u) {
    unsigned lo = ((u & 0x00FFu) << 8) | ((u & 0xFF00u) << 16);
    unsigned hi = ((u & 0xFF0000u) >> 8) | (u & 0xFF000000u);
    __half2 hlo = *(__half2*)&lo, hhi = *(__half2*)&hi;
    float2 flo = __half22float2(hlo), fhi = __half22float2(hhi);
    return make_float4(flo.x, flo.y, fhi.x, fhi.y);
}

// ---------------------------------------------------------------------------
// Pass A: per-(block,bucket) edge counts via LDS histogram (no global atomics)
// + graph node counts via sorted-batch boundary detection + zero pooled[].
__global__ __launch_bounds__(256) void bucket_count(const int* __restrict__ col,
                                                    const int* __restrict__ batch,
                                                    int* __restrict__ counts,
                                                    int* __restrict__ beg,
                                                    int* __restrict__ endx,
                                                    float* __restrict__ pooled) {
    __shared__ int hist[256];
    int tid = threadIdx.x, blk = blockIdx.x;
    hist[tid] = 0;
    __syncthreads();
    int base = blk * 4096;
#pragma unroll
    for (int k = 0; k < 16; ++k) {
        int e = base + k * 256 + tid;
        if (e < NE) atomicAdd(&hist[col[e] >> 8], 1);
    }
    int t = blk * 256 + tid;
    if (t < NG * HD) pooled[t] = 0.f;          // 50176 threads >= 32768
    if (t < NN) {
        int g = batch[t];
        if (t == 0 || batch[t - 1] != g) beg[g] = t;
        if (t == NN - 1 || batch[t + 1] != g) endx[g] = t + 1;
    }
    __syncthreads();
    if (tid < NBK) counts[tid * NBL + blk] = hist[tid];  // bucket-major
}

// ---- 3-stage exclusive scan over counts[M_CNT] ----------------------------
__global__ __launch_bounds__(256) void block_reduce(const int* __restrict__ src,
                                                    int* __restrict__ bsum) {
    __shared__ int ws[4];
    int tid = threadIdx.x, lane = tid & 63, wid = tid >> 6;
    int i = blockIdx.x * 256 + tid;
    int v = (i < M_CNT) ? src[i] : 0;
#pragma unroll
    for (int off = 32; off > 0; off >>= 1) v += __shfl_down(v, off, 64);
    if (lane == 0) ws[wid] = v;
    __syncthreads();
    if (tid == 0) bsum[blockIdx.x] = ws[0] + ws[1] + ws[2] + ws[3];
}

__global__ __launch_bounds__(64) void scan_bsum(int* __restrict__ bsum) {
    int lane = threadIdx.x;
    int carry = 0;
    for (int base = 0; base < NBS; base += 64) {
        int i = base + lane;
        int v = (i < NBS) ? bsum[i] : 0;
        int inc = v;
#pragma unroll
        for (int off = 1; off < 64; off <<= 1) {
            int t = __shfl_up(inc, off, 64);
            if (lane >= off) inc += t;
        }
        if (i < NBS) bsum[i] = carry + inc - v;  // exclusive
        carry += __shfl(inc, 63, 64);
    }
}

__global__ __launch_bounds__(256) void block_scan(const int* __restrict__ src,
                                                  const int* __restrict__ bsum,
                                                  int* __restrict__ dst) {
    __shared__ int ws[4];
    int tid = threadIdx.x, lane = tid & 63, wid = tid >> 6;
    int i = blockIdx.x * 256 + tid;
    int v = (i < M_CNT) ? src[i] : 0;
    int inc = v;
#pragma unroll
    for (int off = 1; off < 64; off <<= 1) {
        int t = __shfl_up(inc, off, 64);
        if (lane >= off) inc += t;
    }
    if (lane == 63) ws[wid] = inc;
    __syncthreads();
    int woff = 0;
    for (int k = 0; k < wid; ++k) woff += ws[k];
    if (i < M_CNT) dst[i] = bsum[blockIdx.x] + woff + inc - v;
}

// ---------------------------------------------------------------------------
// Fused: blocks [0,GEMM_BLOCKS) do h32 = x @ W1 (fp32 out, scaled+quantized by
// csr_build); blocks [GEMM_BLOCKS, +NBL) scatter edges into packed[].
__global__ __launch_bounds__(256) void gemm1_scatter(const float* __restrict__ x,
                                                     const float* __restrict__ W1,
                                                     float* __restrict__ h32,
                                                     const int* __restrict__ row,
                                                     const int* __restrict__ col,
                                                     const int* __restrict__ counts_ex,
                                                     unsigned* __restrict__ packed) {
    if (blockIdx.x < GEMM_BLOCKS) {
        __shared__ float Ws[64][64];   // 16 KB
        __shared__ float Is[16][64];   // 4 KB
        int t = threadIdx.x;
        for (int i = t; i < 64 * 64; i += 256) Ws[i >> 6][i & 63] = W1[i];
        int row0 = blockIdx.x * 16;
        for (int i = t; i < 16 * 64; i += 256)
            Is[i >> 6][i & 63] = x[(row0 + (i >> 6)) * HD + (i & 63)];
        __syncthreads();
        int c = t & 63, r4 = t >> 6;
        float a0 = 0.f, a1 = 0.f, a2 = 0.f, a3 = 0.f;
#pragma unroll
        for (int k = 0; k < 64; ++k) {
            float w = Ws[k][c];
            a0 += Is[r4 + 0][k] * w;
            a1 += Is[r4 + 4][k] * w;
            a2 += Is[r4 + 8][k] * w;
            a3 += Is[r4 + 12][k] * w;
        }
        h32[(row0 + r4 + 0) * HD + c] = a0;
        h32[(row0 + r4 + 4) * HD + c] = a1;
        h32[(row0 + r4 + 8) * HD + c] = a2;
        h32[(row0 + r4 + 12) * HD + c] = a3;
    } else {
        __shared__ int cur[256];
        int tid = threadIdx.x, blk = blockIdx.x - GEMM_BLOCKS;
        cur[tid] = 0;
        __syncthreads();
        int base = blk * 4096;
#pragma unroll
        for (int k = 0; k < 16; ++k) {
            int e = base + k * 256 + tid;
            if (e < NE) {
                int c = col[e], r = row[e];
                int b = c >> 8;
                int lpos = atomicAdd(&cur[b], 1);
                int pos = counts_ex[b * NBL + blk] + lpos;
                packed[pos] = (unsigned)r | ((unsigned)(c & 255) << 16);
            }
        }
    }
}

// ---------------------------------------------------------------------------
// Fused CSR build: per 256-col bucket — (1) histogram+scan -> rowptr/dinv,
// (1.5) h8 = e5m2(dinv * h32) for this bucket's rows [single quantization],
// (2) fill esrc via LDS cursors.
__global__ __launch_bounds__(256) void csr_build(const unsigned* __restrict__ packed,
                                                 const int* __restrict__ counts_ex,
                                                 int* __restrict__ rowptr,
                                                 float* __restrict__ dinv,
                                                 const float* __restrict__ h32,
                                                 unsigned char* __restrict__ h8,
                                                 int* __restrict__ esrc) {
    __shared__ int hist[256];
    __shared__ int ws[4];
    __shared__ int lrp[256];
    __shared__ float sdinv[256];
    int bkt = blockIdx.x, tid = threadIdx.x;
    int s = counts_ex[bkt * NBL];
    int e = (bkt == NBK - 1) ? NE : counts_ex[(bkt + 1) * NBL];
    hist[tid] = 0;
    __syncthreads();
    for (int j = s + tid; j < e; j += 256)
        atomicAdd(&hist[(packed[j] >> 16) & 255], 1);
    __syncthreads();
    int lane = tid & 63, wid = tid >> 6;
    int v = hist[tid], inc = v;
#pragma unroll
    for (int off = 1; off < 64; off <<= 1) {
        int t = __shfl_up(inc, off, 64);
        if (lane >= off) inc += t;
    }
    if (lane == 63) ws[wid] = inc;
    __syncthreads();
    int woff = 0;
    for (int k = 0; k < wid; ++k) woff += ws[k];
    int excl = s + woff + inc - v;               // exclusive scan
    int node = bkt * 256 + tid;
    float dv = rsqrtf((float)(v + 1));           // +1 self-loop
    if (node < NN) {
        rowptr[node] = excl;
        dinv[node] = dv;
    }
    if (bkt == 0 && tid == 0) rowptr[NN] = NE;
    lrp[tid] = excl;
    sdinv[tid] = dv;
    hist[tid] = 0;                               // reuse as fill cursor
    __syncthreads();
    // (1.5) quantize rows of this bucket: h8 = e5m2(dinv * h32)
    {
        int nrows = (bkt == NBK - 1) ? (NN - 195 * 256) : 256;
        const float4* hb32 = (const float4*)(h32 + (size_t)bkt * 256 * HD);
        unsigned* hb8 = (unsigned*)(h8 + (size_t)bkt * 256 * HD);
        for (int i = tid; i < nrows * 16; i += 256) {
            float d = sdinv[i >> 4];             // 16 words per row
            float4 f = hb32[i];
            unsigned u = (unsigned)cv8(d * f.x) |
                         ((unsigned)cv8(d * f.y) << 8) |
                         ((unsigned)cv8(d * f.z) << 16) |
                         ((unsigned)cv8(d * f.w) << 24);
            hb8[i] = u;
        }
    }
    // (2) fill
    for (int j = s + tid; j < e; j += 256) {
        unsigned p = packed[j];
        int lc = (p >> 16) & 255;
        int slot = lrp[lc] + atomicAdd(&hist[lc], 1);
        esrc[slot] = (int)(p & 0xFFFF);          // NN < 65536
    }
}

// ---------------------------------------------------------------------------
// h8 = e5m2(dinv * (relu(in16) @ W))   (layers 2,3)
__global__ __launch_bounds__(256) void gemm64_f16(const __half* __restrict__ in,
                                                  const float* __restrict__ W,
                                                  const float* __restrict__ dinv,
                                                  unsigned char* __restrict__ out8) {
    __shared__ float Ws[64][64];
    __shared__ float Is[16][64];
    __shared__ float sdinv[16];
    int t = threadIdx.x;
    for (int i = t; i < 64 * 64; i += 256) Ws[i >> 6][i & 63] = W[i];
    int row0 = blockIdx.x * 16;
    if (t < 16) sdinv[t] = dinv[row0 + t];
    const __half2* in2 = (const __half2*)(in + (size_t)row0 * HD);
    for (int i = t; i < 16 * 32; i += 256) {
        float2 v = __half22float2(in2[i]);
        int r = i >> 5, c2 = (i & 31) * 2;
        Is[r][c2]     = fmaxf(v.x, 0.f);
        Is[r][c2 + 1] = fmaxf(v.y, 0.f);
    }
    __syncthreads();
    int c = t & 63, r4 = t >> 6;
    float a0 = 0.f, a1 = 0.f, a2 = 0.f, a3 = 0.f;
#pragma unroll
    for (int k = 0; k < 64; ++k) {
        float w = Ws[k][c];
        a0 += Is[r4 + 0][k] * w;
        a1 += Is[r4 + 4][k] * w;
        a2 += Is[r4 + 8][k] * w;
        a3 += Is[r4 + 12][k] * w;
    }
    out8[(size_t)(row0 + r4 + 0) * HD + c] = cv8(a0 * sdinv[r4 + 0]);
    out8[(size_t)(row0 + r4 + 4) * HD + c] = cv8(a1 * sdinv[r4 + 4]);
    out8[(size_t)(row0 + r4 + 8) * HD + c] = cv8(a2 * sdinv[r4 + 8]);
    out8[(size_t)(row0 + r4 + 12) * HD + c] = cv8(a3 * sdinv[r4 + 12]);
}

// ---------------------------------------------------------------------------
// fp8 scalar-stream gather, masked tail. ONE node per wave.
// Lane = 16*q + c4: 4 edges (q) x 16 4-byte chunks (c4) per VMEM -> one 64 B
// row per 16 lanes, 4 rows in flight per instruction batch. 16-edge batches;
// remainder handled by ONE masked batch (srcs clamped, zero-multiplied).
template <bool POOL>
__global__ __launch_bounds__(256) void gather_f8(const unsigned char* __restrict__ h8,
                                                 const int* __restrict__ rowptr,
                                                 const int* __restrict__ esrc,
                                                 const float* __restrict__ dinv,
                                                 const float* __restrict__ b,
                                                 __half* __restrict__ out16,
                                                 const int* __restrict__ batch,
                                                 float* __restrict__ pooled) {
    int tid = threadIdx.x, lane = tid & 63, wid = tid >> 6;
    int q = lane >> 4, c4 = lane & 15;          // edge-in-quad, 4-byte chunk
    bool q0 = (q & 1) != 0, q1 = (q & 2) != 0;
    int node = __builtin_amdgcn_readfirstlane(blockIdx.x * 4 + wid);
    const unsigned* hw = (const unsigned*)h8;   // [NN][16] words
    int s = rowptr[node], e = rowptr[node + 1];     // scalar loads
    float4 acc = {0.f, 0.f, 0.f, 0.f};
    int j = s;
    for (; j + 16 <= e; j += 16) {              // unmasked full batches
        int t0 = esrc[j + 0],  t1 = esrc[j + 1],  t2 = esrc[j + 2],  t3 = esrc[j + 3];
        int t4 = esrc[j + 4],  t5 = esrc[j + 5],  t6 = esrc[j + 6],  t7 = esrc[j + 7];
        int t8 = esrc[j + 8],  t9 = esrc[j + 9],  ta = esrc[j + 10], tb = esrc[j + 11];
        int tc = esrc[j + 12], td = esrc[j + 13], te = esrc[j + 14], tf = esrc[j + 15];
        int a0 = q1 ? (q0 ? t3 : t2) : (q0 ? t1 : t0);
        int a1 = q1 ? (q0 ? t7 : t6) : (q0 ? t5 : t4);
        int a2 = q1 ? (q0 ? tb : ta) : (q0 ? t9 : t8);
        int a3 = q1 ? (q0 ? tf : te) : (q0 ? td : tc);
        unsigned u0 = hw[a0 * 16 + c4];
        unsigned u1 = hw[a1 * 16 + c4];
        unsigned u2 = hw[a2 * 16 + c4];
        unsigned u3 = hw[a3 * 16 + c4];
        float4 f0 = exp8(u0), f1 = exp8(u1), f2 = exp8(u2), f3 = exp8(u3);
        acc.x += (f0.x + f1.x) + (f2.x + f3.x);
        acc.y += (f0.y + f1.y) + (f2.y + f3.y);
        acc.z += (f0.z + f1.z) + (f2.z + f3.z);
        acc.w += (f0.w + f1.w) + (f2.w + f3.w);
    }
    if (j < e) {                                // ONE masked batch (rem 1..15)
        // overrun reads stay in allocated memory; masked src <= 0xFFFF is a
        // safe row index (0xAAAA pad -> 43690 < NN); zero-multiplied.
        int t0 = esrc[j + 0]  & 0xFFFF, t1 = esrc[j + 1]  & 0xFFFF;
        int t2 = esrc[j + 2]  & 0xFFFF, t3 = esrc[j + 3]  & 0xFFFF;
        int t4 = esrc[j + 4]  & 0xFFFF, t5 = esrc[j + 5]  & 0xFFFF;
        int t6 = esrc[j + 6]  & 0xFFFF, t7 = esrc[j + 7]  & 0xFFFF;
        int t8 = esrc[j + 8]  & 0xFFFF, t9 = esrc[j + 9]  & 0xFFFF;
        int ta = esrc[j + 10] & 0xFFFF, tb = esrc[j + 11] & 0xFFFF;
        int tc = esrc[j + 12] & 0xFFFF, td = esrc[j + 13] & 0xFFFF;
        int te = esrc[j + 14] & 0xFFFF, tf = esrc[j + 15] & 0xFFFF;
        int a0 = q1 ? (q0 ? t3 : t2) : (q0 ? t1 : t0);
        int a1 = q1 ? (q0 ? t7 : t6) : (q0 ? t5 : t4);
        int a2 = q1 ? (q0 ? tb : ta) : (q0 ? t9 : t8);
        int a3 = q1 ? (q0 ? tf : te) : (q0 ? td : tc);
        int i0 = j + q, i1 = j + 4 + q, i2 = j + 8 + q, i3 = j + 12 + q;
        a0 = (i0 < e) ? a0 : t0;
        a1 = (i1 < e) ? a1 : t0;
        a2 = (i2 < e) ? a2 : t0;
        a3 = (i3 < e) ? a3 : t0;
        float m0 = (i0 < e) ? 1.f : 0.f;
        float m1 = (i1 < e) ? 1.f : 0.f;
        float m2 = (i2 < e) ? 1.f : 0.f;
        float m3 = (i3 < e) ? 1.f : 0.f;
        unsigned u0 = hw[a0 * 16 + c4];
        unsigned u1 = hw[a1 * 16 + c4];
        unsigned u2 = hw[a2 * 16 + c4];
        unsigned u3 = hw[a3 * 16 + c4];
        float4 f0 = exp8(u0), f1 = exp8(u1), f2 = exp8(u2), f3 = exp8(u3);
        acc.x += m0 * f0.x + m1 * f1.x + m2 * f2.x + m3 * f3.x;
        acc.y += m0 * f0.y + m1 * f1.y + m2 * f2.y + m3 * f3.y;
        acc.z += m0 * f0.z + m1 * f1.z + m2 * f2.z + m3 * f3.z;
        acc.w += m0 * f0.w + m1 * f1.w + m2 * f2.w + m3 * f3.w;
    }
    // combine the 4 quad partials (lanes with equal c4 hold same channels);
    // all 64 lanes active — wave-uniform control flow.
    acc.x += __shfl_xor(acc.x, 16, 64);
    acc.y += __shfl_xor(acc.y, 16, 64);
    acc.z += __shfl_xor(acc.z, 16, 64);
    acc.w += __shfl_xor(acc.w, 16, 64);
    acc.x += __shfl_xor(acc.x, 32, 64);
    acc.y += __shfl_xor(acc.y, 32, 64);
    acc.z += __shfl_xor(acc.z, 32, 64);
    acc.w += __shfl_xor(acc.w, 32, 64);
    if (q == 0) {                               // lanes 0..15
        float di = dinv[node];                  // scalar load
        float4 self = exp8(hw[node * 16 + c4]); // h' already scaled
        float4 bb = ((const float4*)b)[c4];
        float v0 = di * (acc.x + self.x) + bb.x;
        float v1 = di * (acc.y + self.y) + bb.y;
        float v2 = di * (acc.z + self.z) + bb.z;
        float v3 = di * (acc.w + self.w) + bb.w;
        if (POOL) {
            int g = batch[node];
            float* pg = &pooled[g * HD + 4 * c4];
            atomicAdd(pg + 0, v0);
            atomicAdd(pg + 1, v1);
            atomicAdd(pg + 2, v2);
            atomicAdd(pg + 3, v3);
        } else {
            union { struct { __half2 a, b; } h; uint2 u; } cv;
            cv.h.a = __floats2half2_rn(v0, v1);
            cv.h.b = __floats2half2_rn(v2, v3);
            ((uint2*)out16)[(size_t)node * 16 + c4] = cv.u;
        }
    }
}

// out[g] = (pooled[g,:]/max(cnt,1)) . lin_W + lin_b   — one wave per graph
__global__ __launch_bounds__(64) void final_kernel(const float* __restrict__ pooled,
                                                   const int* __restrict__ beg,
                                                   const int* __restrict__ endx,
                                                   const float* __restrict__ lin_W,
                                                   const float* __restrict__ lin_b,
                                                   float* __restrict__ out) {
    int g = blockIdx.x, d = threadIdx.x;
    float cnt = (float)(endx[g] - beg[g]);
    float v = pooled[g * HD + d] / fmaxf(cnt, 1.f) * lin_W[d];
#pragma unroll
    for (int off = 32; off > 0; off >>= 1) v += __shfl_down(v, off, 64);
    if (d == 0) out[g] = v + lin_b[0];
}

// ---------------------------------------------------------------------------
extern "C" void kernel_launch(void* const* d_in, const int* in_sizes, int n_in,
                              void* d_out, int out_size, void* d_ws, size_t ws_size,
                              hipStream_t stream) {
    const float* x     = (const float*)d_in[0];
    const float* W1    = (const float*)d_in[1];
    const float* b1    = (const float*)d_in[2];
    const float* W2    = (const float*)d_in[3];
    const float* b2    = (const float*)d_in[4];
    const float* W3    = (const float*)d_in[5];
    const float* b3    = (const float*)d_in[6];
    const float* lin_W = (const float*)d_in[7];
    const float* lin_b = (const float*)d_in[8];
    const int* edge_index = (const int*)d_in[9];   // [2, NE]: row then col
    const int* batch      = (const int*)d_in[10];
    const int* row = edge_index;
    const int* col = edge_index + NE;
    float* out = (float*)d_out;

    // workspace layout (4B units):
    // [h32 NN*HD f32][A16 NN*HD half][h8 NN*HD bytes][esrc NE+64][packed NE]
    // [counts M][counts_ex M][rowptr NN+2][dinv NN][bsum 256]
    // [pooled NG*HD][beg NG][endx NG]
    float*         h32       = (float*)d_ws;
    __half*        A16       = (__half*)(h32 + (size_t)NN * HD);
    unsigned char* h8        = (unsigned char*)(A16 + (size_t)NN * HD);
    int*           esrc      = (int*)(h8 + (size_t)NN * HD);
    unsigned*      packed    = (unsigned*)(esrc + NE + 64);
    int*           counts    = (int*)(packed + NE);
    int*           counts_ex = counts + M_CNT;
    int*           rowptr    = counts_ex + M_CNT;
    float*         dinv      = (float*)(rowptr + NN + 2);
    int*           bsum      = (int*)(dinv + NN);
    float*         pooled    = (float*)(bsum + 256);
    int*           beg       = (int*)(pooled + NG * HD);
    int*           endx      = beg + NG;

    // CSR build: count(+zero pooled) -> scan -> (scatter fused w/ gemm1)
    //            -> fused rowptr+quantize+fill
    bucket_count<<<NBL, 256, 0, stream>>>(col, batch, counts, beg, endx, pooled);
    block_reduce<<<NBS, 256, 0, stream>>>(counts, bsum);
    scan_bsum<<<1, 64, 0, stream>>>(bsum);
    block_scan<<<NBS, 256, 0, stream>>>(counts, bsum, counts_ex);
    gemm1_scatter<<<GEMM_BLOCKS + NBL, 256, 0, stream>>>(x, W1, h32, row, col,
                                                         counts_ex, packed);
    csr_build<<<NBK, 256, 0, stream>>>(packed, counts_ex, rowptr, dinv,
                                       h32, h8, esrc);

    const int GB = NN / 4;  // gather blocks: 4 nodes (waves) each

    // Layer 1 aggregate: h8(=h1') -> A16
    gather_f8<false><<<GB, 256, 0, stream>>>(h8, rowptr, esrc, dinv, b1, A16,
                                             batch, pooled);
    // Layer 2: relu(A16) -> h8(=h2') -> A16
    gemm64_f16<<<GEMM_BLOCKS, 256, 0, stream>>>(A16, W2, dinv, h8);
    gather_f8<false><<<GB, 256, 0, stream>>>(h8, rowptr, esrc, dinv, b2, A16,
                                             batch, pooled);
    // Layer 3: relu(A16) -> h8(=h3') -> pooled (fused)
    gemm64_f16<<<GEMM_BLOCKS, 256, 0, stream>>>(A16, W3, dinv, h8);
    gather_f8<true><<<GB, 256, 0, stream>>>(h8, rowptr, esrc, dinv, b3, nullptr,
                                            batch, pooled);

    final_kernel<<<NG, 64, 0, stream>>>(pooled, beg, endx, lin_W, lin_b, out);
}

// Round 17
// 267.250 us; speedup vs baseline: 1.0646x; 1.0646x over previous
//
#include <hip/hip_runtime.h>
#include <hip/hip_fp16.h>

// Problem constants (fixed by the reference file)
#define NN 50000     // nodes
#define NE 800000    // edges
#define HD 64        // feature dim (in and hidden)
#define NG 512       // graphs
#define NBK 196      // buckets: col >> 8, max 49999>>8 = 195
#define NBL 196      // edge blocks of 4096: ceil(NE/4096)
#define M_CNT (NBK * NBL)       // 38416 counts
#define NBS 151                 // scan blocks: ceil(M_CNT/256)
#define GEMM_BLOCKS 3125        // NN/16

// Math: out[c] = dinv[c]*(sum_src dinv[src]*h[src]) + dinv[c]^2*h[c] + b.
// h stored UNSCALED fp16 (single rounding from the fp32 GEMM accumulator);
// per-edge weight dinv[src] loaded on the SCALAR pipe per 8-edge batch and
// applied in fp32 (R12's proven-numerics path). Gather keeps R15's shape:
// node-per-wave, scalar esrc stream, unmasked 8-edge batches + ONE masked
// batch tail (srcs clamped &0xFFFF — pad is 0xAA poison — zero-weighted).
// No shuffles in loops (R8/R10 bug), no LDS float atomics (R14), no fp8
// payload (R16 regression: unpack chain + write blowup beat the line savings).

// ---------------------------------------------------------------------------
// Pass A: per-(block,bucket) edge counts via LDS histogram (no global atomics)
// + graph node counts via sorted-batch boundary detection + zero pooled[].
__global__ __launch_bounds__(256) void bucket_count(const int* __restrict__ col,
                                                    const int* __restrict__ batch,
                                                    int* __restrict__ counts,
                                                    int* __restrict__ beg,
                                                    int* __restrict__ endx,
                                                    float* __restrict__ pooled) {
    __shared__ int hist[256];
    int tid = threadIdx.x, blk = blockIdx.x;
    hist[tid] = 0;
    __syncthreads();
    int base = blk * 4096;
#pragma unroll
    for (int k = 0; k < 16; ++k) {
        int e = base + k * 256 + tid;
        if (e < NE) atomicAdd(&hist[col[e] >> 8], 1);
    }
    int t = blk * 256 + tid;
    if (t < NG * HD) pooled[t] = 0.f;          // 50176 threads >= 32768
    if (t < NN) {
        int g = batch[t];
        if (t == 0 || batch[t - 1] != g) beg[g] = t;
        if (t == NN - 1 || batch[t + 1] != g) endx[g] = t + 1;
    }
    __syncthreads();
    if (tid < NBK) counts[tid * NBL + blk] = hist[tid];  // bucket-major
}

// ---- 3-stage exclusive scan over counts[M_CNT] ----------------------------
__global__ __launch_bounds__(256) void block_reduce(const int* __restrict__ src,
                                                    int* __restrict__ bsum) {
    __shared__ int ws[4];
    int tid = threadIdx.x, lane = tid & 63, wid = tid >> 6;
    int i = blockIdx.x * 256 + tid;
    int v = (i < M_CNT) ? src[i] : 0;
#pragma unroll
    for (int off = 32; off > 0; off >>= 1) v += __shfl_down(v, off, 64);
    if (lane == 0) ws[wid] = v;
    __syncthreads();
    if (tid == 0) bsum[blockIdx.x] = ws[0] + ws[1] + ws[2] + ws[3];
}

__global__ __launch_bounds__(64) void scan_bsum(int* __restrict__ bsum) {
    int lane = threadIdx.x;
    int carry = 0;
    for (int base = 0; base < NBS; base += 64) {
        int i = base + lane;
        int v = (i < NBS) ? bsum[i] : 0;
        int inc = v;
#pragma unroll
        for (int off = 1; off < 64; off <<= 1) {
            int t = __shfl_up(inc, off, 64);
            if (lane >= off) inc += t;
        }
        if (i < NBS) bsum[i] = carry + inc - v;  // exclusive
        carry += __shfl(inc, 63, 64);
    }
}

__global__ __launch_bounds__(256) void block_scan(const int* __restrict__ src,
                                                  const int* __restrict__ bsum,
                                                  int* __restrict__ dst) {
    __shared__ int ws[4];
    int tid = threadIdx.x, lane = tid & 63, wid = tid >> 6;
    int i = blockIdx.x * 256 + tid;
    int v = (i < M_CNT) ? src[i] : 0;
    int inc = v;
#pragma unroll
    for (int off = 1; off < 64; off <<= 1) {
        int t = __shfl_up(inc, off, 64);
        if (lane >= off) inc += t;
    }
    if (lane == 63) ws[wid] = inc;
    __syncthreads();
    int woff = 0;
    for (int k = 0; k < wid; ++k) woff += ws[k];
    if (i < M_CNT) dst[i] = bsum[blockIdx.x] + woff + inc - v;
}

// ---------------------------------------------------------------------------
// Fused: blocks [0,GEMM_BLOCKS) do h16 = x @ W1 (fp32 acc, single fp16 round);
// blocks [GEMM_BLOCKS, +NBL) scatter edges into bucket-ordered packed[].
__global__ __launch_bounds__(256) void gemm1_scatter(const float* __restrict__ x,
                                                     const float* __restrict__ W1,
                                                     __half* __restrict__ h16,
                                                     const int* __restrict__ row,
                                                     const int* __restrict__ col,
                                                     const int* __restrict__ counts_ex,
                                                     unsigned* __restrict__ packed) {
    if (blockIdx.x < GEMM_BLOCKS) {
        __shared__ float Ws[64][64];   // 16 KB
        __shared__ float Is[16][64];   // 4 KB
        int t = threadIdx.x;
        for (int i = t; i < 64 * 64; i += 256) Ws[i >> 6][i & 63] = W1[i];
        int row0 = blockIdx.x * 16;
        for (int i = t; i < 16 * 64; i += 256)
            Is[i >> 6][i & 63] = x[(row0 + (i >> 6)) * HD + (i & 63)];
        __syncthreads();
        int c = t & 63, r4 = t >> 6;
        float a0 = 0.f, a1 = 0.f, a2 = 0.f, a3 = 0.f;
#pragma unroll
        for (int k = 0; k < 64; ++k) {
            float w = Ws[k][c];
            a0 += Is[r4 + 0][k] * w;
            a1 += Is[r4 + 4][k] * w;
            a2 += Is[r4 + 8][k] * w;
            a3 += Is[r4 + 12][k] * w;
        }
        h16[(row0 + r4 + 0) * HD + c] = __float2half(a0);
        h16[(row0 + r4 + 4) * HD + c] = __float2half(a1);
        h16[(row0 + r4 + 8) * HD + c] = __float2half(a2);
        h16[(row0 + r4 + 12) * HD + c] = __float2half(a3);
    } else {
        __shared__ int cur[256];
        int tid = threadIdx.x, blk = blockIdx.x - GEMM_BLOCKS;
        cur[tid] = 0;
        __syncthreads();
        int base = blk * 4096;
#pragma unroll
        for (int k = 0; k < 16; ++k) {
            int e = base + k * 256 + tid;
            if (e < NE) {
                int c = col[e], r = row[e];
                int b = c >> 8;
                int lpos = atomicAdd(&cur[b], 1);
                int pos = counts_ex[b * NBL + blk] + lpos;
                packed[pos] = (unsigned)r | ((unsigned)(c & 255) << 16);
            }
        }
    }
}

// ---------------------------------------------------------------------------
// Fused CSR build: per 256-col bucket — (1) histogram+scan -> rowptr/dinv,
// (2) fill esrc via LDS cursors. (No h-scale phase: h stays unscaled.)
__global__ __launch_bounds__(256) void csr_build(const unsigned* __restrict__ packed,
                                                 const int* __restrict__ counts_ex,
                                                 int* __restrict__ rowptr,
                                                 float* __restrict__ dinv,
                                                 int* __restrict__ esrc) {
    __shared__ int hist[256];
    __shared__ int ws[4];
    __shared__ int lrp[256];
    int bkt = blockIdx.x, tid = threadIdx.x;
    int s = counts_ex[bkt * NBL];
    int e = (bkt == NBK - 1) ? NE : counts_ex[(bkt + 1) * NBL];
    hist[tid] = 0;
    __syncthreads();
    for (int j = s + tid; j < e; j += 256)
        atomicAdd(&hist[(packed[j] >> 16) & 255], 1);
    __syncthreads();
    int lane = tid & 63, wid = tid >> 6;
    int v = hist[tid], inc = v;
#pragma unroll
    for (int off = 1; off < 64; off <<= 1) {
        int t = __shfl_up(inc, off, 64);
        if (lane >= off) inc += t;
    }
    if (lane == 63) ws[wid] = inc;
    __syncthreads();
    int woff = 0;
    for (int k = 0; k < wid; ++k) woff += ws[k];
    int excl = s + woff + inc - v;               // exclusive scan
    int node = bkt * 256 + tid;
    if (node < NN) {
        rowptr[node] = excl;
        dinv[node] = rsqrtf((float)(v + 1));     // +1 self-loop
    }
    if (bkt == 0 && tid == 0) rowptr[NN] = NE;
    lrp[tid] = excl;
    hist[tid] = 0;                               // reuse as fill cursor
    __syncthreads();
    for (int j = s + tid; j < e; j += 256) {
        unsigned p = packed[j];
        int lc = (p >> 16) & 255;
        int slot = lrp[lc] + atomicAdd(&hist[lc], 1);
        esrc[slot] = (int)(p & 0xFFFF);          // NN < 65536
    }
}

// ---------------------------------------------------------------------------
// h16 = relu(in16) @ W   (layers 2,3) — unscaled output, single fp16 round
__global__ __launch_bounds__(256) void gemm64_f16(const __half* __restrict__ in,
                                                  const float* __restrict__ W,
                                                  __half* __restrict__ out) {
    __shared__ float Ws[64][64];
    __shared__ float Is[16][64];
    int t = threadIdx.x;
    for (int i = t; i < 64 * 64; i += 256) Ws[i >> 6][i & 63] = W[i];
    int row0 = blockIdx.x * 16;
    const __half2* in2 = (const __half2*)(in + (size_t)row0 * HD);
    for (int i = t; i < 16 * 32; i += 256) {
        float2 v = __half22float2(in2[i]);
        int r = i >> 5, c2 = (i & 31) * 2;
        Is[r][c2]     = fmaxf(v.x, 0.f);
        Is[r][c2 + 1] = fmaxf(v.y, 0.f);
    }
    __syncthreads();
    int c = t & 63, r4 = t >> 6;
    float a0 = 0.f, a1 = 0.f, a2 = 0.f, a3 = 0.f;
#pragma unroll
    for (int k = 0; k < 64; ++k) {
        float w = Ws[k][c];
        a0 += Is[r4 + 0][k] * w;
        a1 += Is[r4 + 4][k] * w;
        a2 += Is[r4 + 8][k] * w;
        a3 += Is[r4 + 12][k] * w;
    }
    out[(row0 + r4 + 0) * HD + c] = __float2half(a0);
    out[(row0 + r4 + 4) * HD + c] = __float2half(a1);
    out[(row0 + r4 + 8) * HD + c] = __float2half(a2);
    out[(row0 + r4 + 12) * HD + c] = __float2half(a3);
}

// ---------------------------------------------------------------------------
// Weighted scalar-stream gather, masked tail. ONE node per wave.
// Lane = 32*p + c: 2 edges x 32 half2 channels per VMEM; 8-edge batches give
// 4 row-gathers in flight. Per batch: 8 scalar esrc loads + 8 scalar dinv
// gathers (L2-hot 200 KB). Remainder: ONE masked batch (srcs clamped &0xFFFF,
// weights zeroed). fp32 weights + single fp16 rounding of h = R12 numerics.
template <bool POOL>
__global__ __launch_bounds__(256) void gather_wt(const __half* __restrict__ hp,
                                                 const int* __restrict__ rowptr,
                                                 const int* __restrict__ esrc,
                                                 const float* __restrict__ dinv,
                                                 const float* __restrict__ b,
                                                 __half* __restrict__ out16,
                                                 const int* __restrict__ batch,
                                                 float* __restrict__ pooled) {
    int tid = threadIdx.x, lane = tid & 63, wid = tid >> 6;
    int p = lane >> 5, c = lane & 31;           // edge-of-pair, half2 channel
    int node = __builtin_amdgcn_readfirstlane(blockIdx.x * 4 + wid);
    const __half2* hv = (const __half2*)hp;
    int s = rowptr[node], e = rowptr[node + 1];     // scalar loads
    float2 acc = {0.f, 0.f};
    int j = s;
    for (; j + 8 <= e; j += 8) {                // unmasked full batches
        int t0 = esrc[j + 0], t1 = esrc[j + 1], t2 = esrc[j + 2], t3 = esrc[j + 3];
        int t4 = esrc[j + 4], t5 = esrc[j + 5], t6 = esrc[j + 6], t7 = esrc[j + 7];
        float w0 = dinv[t0], w1 = dinv[t1], w2 = dinv[t2], w3 = dinv[t3];
        float w4 = dinv[t4], w5 = dinv[t5], w6 = dinv[t6], w7 = dinv[t7];
        int a0 = p ? t1 : t0;  float u0 = p ? w1 : w0;
        int a1 = p ? t3 : t2;  float u1 = p ? w3 : w2;
        int a2 = p ? t5 : t4;  float u2 = p ? w5 : w4;
        int a3 = p ? t7 : t6;  float u3 = p ? w7 : w6;
        float2 f0 = __half22float2(hv[a0 * 32 + c]);
        float2 f1 = __half22float2(hv[a1 * 32 + c]);
        float2 f2 = __half22float2(hv[a2 * 32 + c]);
        float2 f3 = __half22float2(hv[a3 * 32 + c]);
        acc.x += u0 * f0.x + u1 * f1.x + u2 * f2.x + u3 * f3.x;
        acc.y += u0 * f0.y + u1 * f1.y + u2 * f2.y + u3 * f3.y;
    }
    if (j < e) {                                // ONE masked batch (rem 1..7)
        // overrun reads stay in allocated memory; &0xFFFF keeps row/dinv
        // indices in-bounds (0xAAAA pad -> 43690 < NN); zero-weighted.
        int t0 = esrc[j + 0] & 0xFFFF, t1 = esrc[j + 1] & 0xFFFF;
        int t2 = esrc[j + 2] & 0xFFFF, t3 = esrc[j + 3] & 0xFFFF;
        int t4 = esrc[j + 4] & 0xFFFF, t5 = esrc[j + 5] & 0xFFFF;
        int t6 = esrc[j + 6] & 0xFFFF, t7 = esrc[j + 7] & 0xFFFF;
        float w0 = dinv[t0], w1 = dinv[t1], w2 = dinv[t2], w3 = dinv[t3];
        float w4 = dinv[t4], w5 = dinv[t5], w6 = dinv[t6], w7 = dinv[t7];
        int i0 = j + p, i1 = j + 2 + p, i2 = j + 4 + p, i3 = j + 6 + p;
        int a0 = p ? t1 : t0;  float u0 = p ? w1 : w0;
        int a1 = p ? t3 : t2;  float u1 = p ? w3 : w2;
        int a2 = p ? t5 : t4;  float u2 = p ? w5 : w4;
        int a3 = p ? t7 : t6;  float u3 = p ? w7 : w6;
        a0 = (i0 < e) ? a0 : t0;  u0 = (i0 < e) ? u0 : 0.f;
        a1 = (i1 < e) ? a1 : t0;  u1 = (i1 < e) ? u1 : 0.f;
        a2 = (i2 < e) ? a2 : t0;  u2 = (i2 < e) ? u2 : 0.f;
        a3 = (i3 < e) ? a3 : t0;  u3 = (i3 < e) ? u3 : 0.f;
        float2 f0 = __half22float2(hv[a0 * 32 + c]);
        float2 f1 = __half22float2(hv[a1 * 32 + c]);
        float2 f2 = __half22float2(hv[a2 * 32 + c]);
        float2 f3 = __half22float2(hv[a3 * 32 + c]);
        acc.x += u0 * f0.x + u1 * f1.x + u2 * f2.x + u3 * f3.x;
        acc.y += u0 * f0.y + u1 * f1.y + u2 * f2.y + u3 * f3.y;
    }
    // combine the two edge-pair partials (lane L ^ 32 holds same channel)
    acc.x += __shfl_xor(acc.x, 32, 64);
    acc.y += __shfl_xor(acc.y, 32, 64);
    if (p == 0) {
        float di = dinv[node];                  // scalar load
        float2 self = __half22float2(hv[node * 32 + c]);   // unscaled h
        float2 bb = ((const float2*)b)[c];
        float vx = di * acc.x + di * di * self.x + bb.x;
        float vy = di * acc.y + di * di * self.y + bb.y;
        if (POOL) {
            int g = batch[node];
            atomicAdd(&pooled[g * HD + 2 * c], vx);
            atomicAdd(&pooled[g * HD + 2 * c + 1], vy);
        } else {
            ((__half2*)out16)[node * 32 + c] = __floats2half2_rn(vx, vy);
        }
    }
}

// out[g] = (pooled[g,:]/max(cnt,1)) . lin_W + lin_b   — one wave per graph
__global__ __launch_bounds__(64) void final_kernel(const float* __restrict__ pooled,
                                                   const int* __restrict__ beg,
                                                   const int* __restrict__ endx,
                                                   const float* __restrict__ lin_W,
                                                   const float* __restrict__ lin_b,
                                                   float* __restrict__ out) {
    int g = blockIdx.x, d = threadIdx.x;
    float cnt = (float)(endx[g] - beg[g]);
    float v = pooled[g * HD + d] / fmaxf(cnt, 1.f) * lin_W[d];
#pragma unroll
    for (int off = 32; off > 0; off >>= 1) v += __shfl_down(v, off, 64);
    if (d == 0) out[g] = v + lin_b[0];
}

// ---------------------------------------------------------------------------
extern "C" void kernel_launch(void* const* d_in, const int* in_sizes, int n_in,
                              void* d_out, int out_size, void* d_ws, size_t ws_size,
                              hipStream_t stream) {
    const float* x     = (const float*)d_in[0];
    const float* W1    = (const float*)d_in[1];
    const float* b1    = (const float*)d_in[2];
    const float* W2    = (const float*)d_in[3];
    const float* b2    = (const float*)d_in[4];
    const float* W3    = (const float*)d_in[5];
    const float* b3    = (const float*)d_in[6];
    const float* lin_W = (const float*)d_in[7];
    const float* lin_b = (const float*)d_in[8];
    const int* edge_index = (const int*)d_in[9];   // [2, NE]: row then col
    const int* batch      = (const int*)d_in[10];
    const int* row = edge_index;
    const int* col = edge_index + NE;
    float* out = (float*)d_out;

    // workspace layout (4B units):
    // [h16 NN*HD half][A16 NN*HD half][esrc NE+64][packed NE]
    // [counts M][counts_ex M][rowptr NN+2][dinv NN][bsum 256]
    // [pooled NG*HD][beg NG][endx NG]        total ~20 MB
    __half*   h16       = (__half*)d_ws;
    __half*   A16       = h16 + (size_t)NN * HD;
    int*      esrc      = (int*)(A16 + (size_t)NN * HD);
    unsigned* packed    = (unsigned*)(esrc + NE + 64);
    int*      counts    = (int*)(packed + NE);
    int*      counts_ex = counts + M_CNT;
    int*      rowptr    = counts_ex + M_CNT;
    float*    dinv      = (float*)(rowptr + NN + 2);
    int*      bsum      = (int*)(dinv + NN);
    float*    pooled    = (float*)(bsum + 256);
    int*      beg       = (int*)(pooled + NG * HD);
    int*      endx      = beg + NG;

    // CSR build: count(+zero pooled) -> scan -> (scatter fused w/ gemm1)
    //            -> fused rowptr+fill
    bucket_count<<<NBL, 256, 0, stream>>>(col, batch, counts, beg, endx, pooled);
    block_reduce<<<NBS, 256, 0, stream>>>(counts, bsum);
    scan_bsum<<<1, 64, 0, stream>>>(bsum);
    block_scan<<<NBS, 256, 0, stream>>>(counts, bsum, counts_ex);
    gemm1_scatter<<<GEMM_BLOCKS + NBL, 256, 0, stream>>>(x, W1, h16, row, col,
                                                         counts_ex, packed);
    csr_build<<<NBK, 256, 0, stream>>>(packed, counts_ex, rowptr, dinv, esrc);

    const int GB = NN / 4;  // gather blocks: 4 nodes (waves) each

    // Layer 1 aggregate: h16 -> A16
    gather_wt<false><<<GB, 256, 0, stream>>>(h16, rowptr, esrc, dinv, b1, A16,
                                             batch, pooled);
    // Layer 2: relu(A16) -> h16 -> A16
    gemm64_f16<<<GEMM_BLOCKS, 256, 0, stream>>>(A16, W2, h16);
    gather_wt<false><<<GB, 256, 0, stream>>>(h16, rowptr, esrc, dinv, b2, A16,
                                             batch, pooled);
    // Layer 3: relu(A16) -> h16 -> pooled (fused)
    gemm64_f16<<<GEMM_BLOCKS, 256, 0, stream>>>(A16, W3, h16);
    gather_wt<true><<<GB, 256, 0, stream>>>(h16, rowptr, esrc, dinv, b3, nullptr,
                                            batch, pooled);

    final_kernel<<<NG, 64, 0, stream>>>(pooled, beg, endx, lin_W, lin_b, out);
}